// Round 7
// baseline (1142.886 us; speedup 1.0000x reference)
//
#include <hip/hip_runtime.h>
#include <math.h>

// ---------------- types ----------------
typedef __attribute__((ext_vector_type(8))) short bf16x8;
typedef __attribute__((ext_vector_type(4))) short short4v;
typedef __attribute__((ext_vector_type(4))) float f32x4;

__device__ __forceinline__ float sigm(float x) { return 1.f / (1.f + expf(-x)); }

__device__ __forceinline__ float bf2f(short x) {
    unsigned u = ((unsigned)(unsigned short)x) << 16;
    float f; __builtin_memcpy(&f, &u, 4); return f;
}
__device__ __forceinline__ short f2bf(float f) {
    unsigned u; __builtin_memcpy(&u, &f, 4);
    unsigned r = (u + 0x7fffu + ((u >> 16) & 1u)) >> 16;
    return (short)r;
}

// ---------------- barrier v6: flat packed slots, wave-0 polling --------------
// v6 tree cost ~4 IF hops/step. Flat: arrival = 1 system-relaxed dword store
// into a PACKED 256-dword array (16 lines); wait = wave 0 of every block polls
// all 256 slots with 4 coalesced system loads per lane. 2 hops total.
// Traffic: 64 line-reads/block/sweep, sweep ~1.1us -> ~16K line-reads/us
// grid-wide, ~4x below the all-thread-polling meltdown regime (r5).
// Values monotonic (t+1); slots zeroed in-graph via system-scope stores.
__device__ __forceinline__ unsigned sys_ld(const unsigned* p) {
    return __hip_atomic_load(p, __ATOMIC_RELAXED, __HIP_MEMORY_SCOPE_SYSTEM);
}
__device__ __forceinline__ void sys_st(unsigned* p, unsigned v) {
    __hip_atomic_store(p, v, __ATOMIC_RELAXED, __HIP_MEMORY_SCOPE_SYSTEM);
}

// ---------------- workspace layout (byte offsets) ----------------
#define OFF_C1      0u           // barrier slots: arrive1@0 (1KB), arrive2@4096 (1KB)
#define OFF_H1HI    786432u      // 33 x 64x1024 bf16  4325376 (slot0 never read)
#define OFF_H1LO    5111808u     // 33 x 64x1024 bf16  4325376
#define OFF_H1F     9437184u     // 32 x 64x1024 f32 (lstm1 out) -> reused as
                                 // time-indexed H2 slots by lstm2
#define OFF_X0HI    17825792u    // 2048x1024 bf16 4194304  (aliased by VHI later)
#define OFF_X0LO    22020096u    // 2048x1024 bf16 4194304  (aliased by VLO later)
#define OFF_B1      26214400u    // 4096 f32 16384
#define OFF_B2      26230784u    // 4096 f32 16384
#define OFF_WHH1HI  26247168u    // 4096x1024 bf16 8388608
#define OFF_WHH1LO  34635776u
#define OFF_WIH1HI  43024384u
#define OFF_WIH1LO  51412992u
#define OFF_WHH2HI  59801600u
#define OFF_WVHI    68190208u
#define OFF_WVLO    76578816u
#define OFF_WH2HI   84967424u
#define OFF_X12     93356032u    // 2048x4096 f32 33554432 (also lo-dump during prep)

// ---------------- prep kernels ----------------
__global__ __launch_bounds__(256) void zero_ws(float4* __restrict__ p) {
    int i = blockIdx.x * 256 + threadIdx.x;
    p[i] = make_float4(0.f, 0.f, 0.f, 0.f);
}

// slot region zeroed with SYSTEM-scope (cache-bypass) stores so system polls
// observe the zeros.
__global__ __launch_bounds__(256) void zero_slots(unsigned* __restrict__ p) {
    int i = blockIdx.x * 256 + threadIdx.x;   // 8 blocks -> 2048 u32 = 8KB
    __hip_atomic_store(p + i, 0u, __ATOMIC_RELAXED, __HIP_MEMORY_SCOPE_SYSTEM);
}

__global__ __launch_bounds__(256) void perm_w_split(const float* __restrict__ src,
                                                    short* __restrict__ hi,
                                                    short* __restrict__ lo,
                                                    int rs, int co) {
    int idx = blockIdx.x * 256 + threadIdx.x;   // 4096 blocks
    int jp = idx >> 8;
    int kq = idx & 255;
    int jsrc = (jp & 3) * 1024 + (jp >> 2);
    float4 v = *(const float4*)(src + (size_t)jsrc * rs + co + kq * 4);
    float a[4] = {v.x, v.y, v.z, v.w};
    short4v h, l;
    #pragma unroll
    for (int e = 0; e < 4; e++) {
        short q = f2bf(a[e]);
        h[e] = q;
        l[e] = f2bf(a[e] - bf2f(q));
    }
    *(short4v*)(hi + (size_t)jp * 1024 + kq * 4) = h;
    *(short4v*)(lo + (size_t)jp * 1024 + kq * 4) = l;
}

__global__ __launch_bounds__(256) void bias_prep(
    const float* __restrict__ bi1, const float* __restrict__ bh1,
    const float* __restrict__ bi2, const float* __restrict__ bh2,
    float* __restrict__ b1p, float* __restrict__ b2p) {
    int jp = blockIdx.x * 256 + threadIdx.x;     // 16 blocks
    int j = (jp & 3) * 1024 + (jp >> 2);
    b1p[jp] = bi1[j] + bh1[j];
    b2p[jp] = bi2[j] + bh2[j];
}

__global__ __launch_bounds__(256) void gather_x0_split(
    const int* __restrict__ tokens, const float* __restrict__ emb,
    short* __restrict__ hi, short* __restrict__ lo) {
    int idx = blockIdx.x * 256 + threadIdx.x;    // 2048 blocks
    int p = idx >> 8;
    int k0 = (idx & 255) * 4;
    int tok = tokens[p];
    float4 v = *(const float4*)(emb + (size_t)tok * 1024 + k0);
    float a[4] = {v.x, v.y, v.z, v.w};
    short4v h, l;
    #pragma unroll
    for (int e = 0; e < 4; e++) {
        short q = f2bf(a[e]);
        h[e] = q;
        l[e] = f2bf(a[e] - bf2f(q));
    }
    *(short4v*)(hi + (size_t)p * 1024 + k0) = h;
    *(short4v*)(lo + (size_t)p * 1024 + k0) = l;
}

// ---------------- big GEMM (unchanged) ----------------
__global__ __launch_bounds__(256) void big_gemm(
    const short* __restrict__ A0, const short* __restrict__ A1s,
    const short* __restrict__ A2s, const short* __restrict__ A3s,
    const short* __restrict__ B0, const short* __restrict__ B1s,
    const short* __restrict__ B2s, const short* __restrict__ B3s,
    const float* __restrict__ bias, float* __restrict__ C, int K) {
    __shared__ short As[128 * 40];
    __shared__ short Bs[128 * 40];
    int tid = threadIdx.x;
    int n0 = blockIdx.x * 128;
    int m0 = blockIdx.y * 128;
    int lane = tid & 63, w = tid >> 6;
    int wm = (w >> 1) * 64, wn = (w & 1) * 64;
    int quad = lane >> 4, l16 = lane & 15;
    int srow = tid >> 2;
    int skc = (tid & 3) * 8;

    f32x4 acc[4][4];
    f32x4 z4 = {0.f, 0.f, 0.f, 0.f};
    #pragma unroll
    for (int i = 0; i < 4; i++)
        #pragma unroll
        for (int j = 0; j < 4; j++) acc[i][j] = z4;

    for (int k0 = 0; k0 < K; k0 += 32) {
        int seg = k0 >> 10;
        const short* Ab = (seg == 0) ? A0 : (seg == 1) ? A1s : (seg == 2) ? A2s : A3s;
        const short* Bb = (seg == 0) ? B0 : (seg == 1) ? B1s : (seg == 2) ? B2s : B3s;
        int kk = (k0 & 1023) + skc;
        const short* ga = Ab + (size_t)(m0 + srow) * 1024 + kk;
        const short* gb = Bb + (size_t)(n0 + srow) * 1024 + kk;
        bf16x8 av0 = *(const bf16x8*)ga;
        bf16x8 av1 = *(const bf16x8*)(ga + 64 * 1024);
        bf16x8 bv0 = *(const bf16x8*)gb;
        bf16x8 bv1 = *(const bf16x8*)(gb + 64 * 1024);
        __syncthreads();
        *(bf16x8*)&As[srow * 40 + skc] = av0;
        *(bf16x8*)&As[(srow + 64) * 40 + skc] = av1;
        *(bf16x8*)&Bs[srow * 40 + skc] = bv0;
        *(bf16x8*)&Bs[(srow + 64) * 40 + skc] = bv1;
        __syncthreads();
        bf16x8 af[4], bfr[4];
        #pragma unroll
        for (int im = 0; im < 4; im++)
            af[im] = *(const bf16x8*)&As[(wm + im * 16 + l16) * 40 + quad * 8];
        #pragma unroll
        for (int in = 0; in < 4; in++)
            bfr[in] = *(const bf16x8*)&Bs[(wn + in * 16 + l16) * 40 + quad * 8];
        #pragma unroll
        for (int im = 0; im < 4; im++)
            #pragma unroll
            for (int in = 0; in < 4; in++)
                acc[im][in] = __builtin_amdgcn_mfma_f32_16x16x32_bf16(
                    af[im], bfr[in], acc[im][in], 0, 0, 0);
    }
    #pragma unroll
    for (int in = 0; in < 4; in++) {
        int j = n0 + wn + in * 16 + l16;
        float bsv = bias[j];
        #pragma unroll
        for (int im = 0; im < 4; im++) {
            #pragma unroll
            for (int r = 0; r < 4; r++) {
                int p = m0 + wm + im * 16 + quad * 4 + r;
                C[(size_t)p * 4096 + j] = acc[im][in][r] + bsv;
            }
        }
    }
}

// ---------------- fused layer-1 recurrence (persistent, flat barrier) --------
// 256 blocks x 256 thr. Block g owns gate-rows [g*16,g*16+16) of whh1.
// W-hi in LDS; W-lo from global (L2-resident). Cell state register-resident.
// h written via shfl-gathered 8B sc1 stores (64/block/buffer) into
// TIME-INDEXED slots; t=0 skips h@W MFMA. Tail: gather-stores -> syncthreads
// (drain) -> packed arrival -> H1f store + X12[t+1] prefetch -> wave0 flat poll.
__global__ __launch_bounds__(256, 1) void lstm1_fused(
    const short* __restrict__ Whi, const short* __restrict__ Wlo,
    const float* __restrict__ X12,
    short* __restrict__ H1hi, short* __restrict__ H1lo,
    float* __restrict__ H1f,
    unsigned* __restrict__ arrive) {
    __shared__ short wsh[16 * 1032];
    __shared__ float red[4 * 64 * 16];

    int tid = threadIdx.x;
    int lane = tid & 63, w = tid >> 6;
    int quad = lane >> 4, l16 = lane & 15;
    int g = blockIdx.x;
    int kbase = w * 256;

    // stage hi-weight slice into LDS once
    for (int i = tid; i < 2048; i += 256) {
        int r = i >> 7;
        int k = (i & 127) * 8;
        *(bf16x8*)&wsh[r * 1032 + k] =
            *(const bf16x8*)(Whi + (size_t)(g * 16 + r) * 1024 + k);
    }

    int s = tid >> 2, dl = tid & 3;
    int d = g * 4 + dl;
    float creg = 0.f;           // register-resident cell state

    __syncthreads();

    const short* bhp = &wsh[l16 * 1032 + kbase + quad * 8];
    const short* blp = Wlo + (size_t)(g * 16 + l16) * 1024 + kbase + quad * 8;
    const float* xgp = X12 + (size_t)s * 4096 + g * 16 + dl * 4;

    float4 xg = *(const float4*)xgp;   // step-0 gate-bias slice

    for (int t = 0; t < 32; t++) {
        f32x4 acc[4];
        f32x4 z4 = {0.f, 0.f, 0.f, 0.f};
        acc[0] = z4; acc[1] = z4; acc[2] = z4; acc[3] = z4;

        if (t > 0) {   // h1[0] == 0 -> skip MFMA at t=0
            const short* ah = H1hi + (size_t)t * 65536 + (size_t)l16 * 1024 + kbase + quad * 8;
            const short* al = H1lo + (size_t)t * 65536 + (size_t)l16 * 1024 + kbase + quad * 8;
            #pragma unroll
            for (int i = 0; i < 8; i++) {
                int k = i * 32;
                bf16x8 Bh = *(const bf16x8*)(bhp + k);
                bf16x8 Bl = *(const bf16x8*)(blp + k);
                #pragma unroll
                for (int mt = 0; mt < 4; mt++) {
                    bf16x8 Ah = *(const bf16x8*)(ah + mt * 16 * 1024 + k);
                    bf16x8 Al = *(const bf16x8*)(al + mt * 16 * 1024 + k);
                    acc[mt] = __builtin_amdgcn_mfma_f32_16x16x32_bf16(Ah, Bh, acc[mt], 0, 0, 0);
                    acc[mt] = __builtin_amdgcn_mfma_f32_16x16x32_bf16(Al, Bh, acc[mt], 0, 0, 0);
                    acc[mt] = __builtin_amdgcn_mfma_f32_16x16x32_bf16(Ah, Bl, acc[mt], 0, 0, 0);
                }
            }
        }
        #pragma unroll
        for (int mt = 0; mt < 4; mt++)
            #pragma unroll
            for (int r = 0; r < 4; r++) {
                int sr = mt * 16 + quad * 4 + r;
                red[(w * 64 + sr) * 16 + l16] = acc[mt][r];
            }
        __syncthreads();

        float gi = 0.f, gf = 0.f, gg = 0.f, go = 0.f;
        #pragma unroll
        for (int w2 = 0; w2 < 4; w2++) {
            const float* rp = &red[(w2 * 64 + s) * 16 + dl * 4];
            gi += rp[0]; gf += rp[1]; gg += rp[2]; go += rp[3];
        }
        gi += xg.x; gf += xg.y; gg += xg.z; go += xg.w;
        float cn = sigm(gf) * creg + sigm(gi) * tanhf(gg);
        creg = cn;
        float hn = sigm(go) * tanhf(cn);
        short q = f2bf(hn);
        short ql = f2bf(hn - bf2f(q));

        // shfl-gather 4 lanes' (q,ql) -> lane dl==0 stores 8B per buffer (sc1)
        unsigned pr = ((unsigned)(unsigned short)q) |
                      (((unsigned)(unsigned short)ql) << 16);
        int lb = lane & ~3;
        unsigned p0 = __shfl(pr, lb + 0, 64);
        unsigned p1 = __shfl(pr, lb + 1, 64);
        unsigned p2 = __shfl(pr, lb + 2, 64);
        unsigned p3 = __shfl(pr, lb + 3, 64);
        if (dl == 0) {
            unsigned long long hi4 =
                (unsigned long long)(p0 & 0xffffu) |
                ((unsigned long long)(p1 & 0xffffu) << 16) |
                ((unsigned long long)(p2 & 0xffffu) << 32) |
                ((unsigned long long)(p3 & 0xffffu) << 48);
            unsigned long long lo4 =
                (unsigned long long)(p0 >> 16) |
                ((unsigned long long)(p1 >> 16) << 16) |
                ((unsigned long long)(p2 >> 16) << 32) |
                ((unsigned long long)(p3 >> 16) << 48);
            __hip_atomic_store(
                (unsigned long long*)&H1hi[(size_t)(t + 1) * 65536 + s * 1024 + g * 4],
                hi4, __ATOMIC_RELAXED, __HIP_MEMORY_SCOPE_AGENT);
            __hip_atomic_store(
                (unsigned long long*)&H1lo[(size_t)(t + 1) * 65536 + s * 1024 + g * 4],
                lo4, __ATOMIC_RELAXED, __HIP_MEMORY_SCOPE_AGENT);
        }
        __syncthreads();                       // drain: gathered stores acked
        if (t != 31) {
            unsigned tgt = (unsigned)(t + 1);
            if (tid == 0) sys_st(arrive + g, tgt);
            // off-chain work, in flight during the wait window:
            H1f[(size_t)t * 65536 + s * 1024 + d] = hn;   // consumed by attn later
            xg = *(const float4*)(xgp + (size_t)(t + 1) * 262144);
            if (tid < 64) {                    // wave 0 polls all 256 slots
                const unsigned* p = arrive + tid * 4;
                for (;;) {
                    unsigned a = sys_ld(p + 0), b = sys_ld(p + 1);
                    unsigned c = sys_ld(p + 2), e = sys_ld(p + 3);
                    int ok = (a >= tgt) && (b >= tgt) && (c >= tgt) && (e >= tgt);
                    if (__all(ok)) break;
                    __builtin_amdgcn_s_sleep(4);
                }
            }
            __syncthreads();
            asm volatile("" ::: "memory");
        } else {
            H1f[(size_t)t * 65536 + s * 1024 + d] = hn;
        }
    }
}

// ---------------- fused layer-2 recurrence (persistent, flat barrier) --------
// H2 is TIME-INDEXED (33 slots, lives in the dead H1F region); t=0 skips MFMA.
__global__ __launch_bounds__(256, 1) void lstm2_fused(
    const short* __restrict__ W, const float* __restrict__ X12,
    short* __restrict__ H2,
    float* __restrict__ out,
    unsigned* __restrict__ arrive) {
    __shared__ short wsh[16 * 1032];
    __shared__ float red[4 * 64 * 16];

    int tid = threadIdx.x;
    int lane = tid & 63, w = tid >> 6;
    int quad = lane >> 4, l16 = lane & 15;
    int g = blockIdx.x;
    int kbase = w * 256;

    for (int i = tid; i < 2048; i += 256) {
        int r = i >> 7;
        int k = (i & 127) * 8;
        *(bf16x8*)&wsh[r * 1032 + k] =
            *(const bf16x8*)(W + (size_t)(g * 16 + r) * 1024 + k);
    }

    int s = tid >> 2, dl = tid & 3;
    int d = g * 4 + dl;
    float creg = 0.f;

    __syncthreads();

    const short* bp = &wsh[l16 * 1032 + kbase + quad * 8];
    const float* xgp = X12 + (size_t)s * 4096 + g * 16 + dl * 4;

    float4 xg = *(const float4*)xgp;

    for (int t = 0; t < 32; t++) {
        f32x4 acc[4];
        f32x4 z4 = {0.f, 0.f, 0.f, 0.f};
        acc[0] = z4; acc[1] = z4; acc[2] = z4; acc[3] = z4;

        if (t > 0) {   // h2[0] == 0 -> skip MFMA at t=0
            const short* ar = H2 + (size_t)t * 65536 + (size_t)l16 * 1024 + kbase + quad * 8;
            #pragma unroll
            for (int i = 0; i < 8; i++) {
                int k = i * 32;
                bf16x8 b = *(const bf16x8*)(bp + k);
                #pragma unroll
                for (int mt = 0; mt < 4; mt++) {
                    bf16x8 a = *(const bf16x8*)(ar + mt * 16 * 1024 + k);
                    acc[mt] = __builtin_amdgcn_mfma_f32_16x16x32_bf16(a, b, acc[mt], 0, 0, 0);
                }
            }
        }
        #pragma unroll
        for (int mt = 0; mt < 4; mt++)
            #pragma unroll
            for (int r = 0; r < 4; r++) {
                int sr = mt * 16 + quad * 4 + r;
                red[(w * 64 + sr) * 16 + l16] = acc[mt][r];
            }
        __syncthreads();

        float gi = 0.f, gf = 0.f, gg = 0.f, go = 0.f;
        #pragma unroll
        for (int w2 = 0; w2 < 4; w2++) {
            const float* rp = &red[(w2 * 64 + s) * 16 + dl * 4];
            gi += rp[0]; gf += rp[1]; gg += rp[2]; go += rp[3];
        }
        gi += xg.x; gf += xg.y; gg += xg.z; go += xg.w;
        float cn = sigm(gf) * creg + sigm(gi) * tanhf(gg);
        creg = cn;
        float hn = sigm(go) * tanhf(cn);

        // shfl-gather 4 lanes' bf16 h -> lane dl==0 stores one 8B sc1 store
        unsigned pr = (unsigned)(unsigned short)f2bf(hn);
        int lb = lane & ~3;
        unsigned p0 = __shfl(pr, lb + 0, 64);
        unsigned p1 = __shfl(pr, lb + 1, 64);
        unsigned p2 = __shfl(pr, lb + 2, 64);
        unsigned p3 = __shfl(pr, lb + 3, 64);
        if (dl == 0) {
            unsigned long long h4 =
                (unsigned long long)(p0 & 0xffffu) |
                ((unsigned long long)(p1 & 0xffffu) << 16) |
                ((unsigned long long)(p2 & 0xffffu) << 32) |
                ((unsigned long long)(p3 & 0xffffu) << 48);
            __hip_atomic_store(
                (unsigned long long*)&H2[(size_t)(t + 1) * 65536 + s * 1024 + g * 4],
                h4, __ATOMIC_RELAXED, __HIP_MEMORY_SCOPE_AGENT);
        }
        __syncthreads();                       // drain
        if (t != 31) {
            unsigned tgt = (unsigned)(t + 1);
            if (tid == 0) sys_st(arrive + g, tgt);
            out[(size_t)t * 65536 + s * 1024 + d] = hn;   // host-visible later
            xg = *(const float4*)(xgp + (size_t)(t + 1) * 262144);
            if (tid < 64) {
                const unsigned* p = arrive + tid * 4;
                for (;;) {
                    unsigned a = sys_ld(p + 0), b = sys_ld(p + 1);
                    unsigned c = sys_ld(p + 2), e = sys_ld(p + 3);
                    int ok = (a >= tgt) && (b >= tgt) && (c >= tgt) && (e >= tgt);
                    if (__all(ok)) break;
                    __builtin_amdgcn_s_sleep(4);
                }
            }
            __syncthreads();
            asm volatile("" ::: "memory");
        } else {
            out[(size_t)t * 65536 + s * 1024 + d] = hn;
        }
    }
}

// ---------------- batched attention (fp32, unchanged) ----------------
__global__ __launch_bounds__(256) void attn_batch(
    const float* __restrict__ H1f, const float* __restrict__ F,
    short* __restrict__ Vhi, short* __restrict__ Vlo) {
    __shared__ float vs[4][4][1024];
    int n = blockIdx.x, tg = blockIdx.y;
    int tid = threadIdx.x, lane = tid & 63, w = tid >> 6;

    float h[4][16];
    #pragma unroll
    for (int tt = 0; tt < 4; tt++) {
        const float* hp = H1f + ((size_t)((tg * 4 + tt) * 64 + n)) * 1024 + lane * 16;
        #pragma unroll
        for (int j = 0; j < 4; j++) {
            float4 v = *(const float4*)(hp + j * 4);
            h[tt][j * 4 + 0] = v.x; h[tt][j * 4 + 1] = v.y;
            h[tt][j * 4 + 2] = v.z; h[tt][j * 4 + 3] = v.w;
        }
    }
    float vacc[4][16];
    #pragma unroll
    for (int tt = 0; tt < 4; tt++)
        #pragma unroll
        for (int j = 0; j < 16; j++) vacc[tt][j] = 0.f;

    const float* Fn = F + ((size_t)n * 196) * 1024 + lane * 16;
    for (int l = w; l < 196; l += 4) {
        const float* fr = Fn + (size_t)l * 1024;
        float f[16];
        #pragma unroll
        for (int j = 0; j < 4; j++) {
            float4 v = *(const float4*)(fr + j * 4);
            f[j * 4 + 0] = v.x; f[j * 4 + 1] = v.y;
            f[j * 4 + 2] = v.z; f[j * 4 + 3] = v.w;
        }
        float p[4] = {0.f, 0.f, 0.f, 0.f};
        #pragma unroll
        for (int tt = 0; tt < 4; tt++)
            #pragma unroll
            for (int j = 0; j < 16; j++) p[tt] += f[j] * h[tt][j];
        #pragma unroll
        for (int off = 32; off > 0; off >>= 1) {
            #pragma unroll
            for (int tt = 0; tt < 4; tt++) p[tt] += __shfl_xor(p[tt], off, 64);
        }
        #pragma unroll
        for (int tt = 0; tt < 4; tt++)
            #pragma unroll
            for (int j = 0; j < 16; j++) vacc[tt][j] += p[tt] * f[j];
    }
    #pragma unroll
    for (int tt = 0; tt < 4; tt++)
        #pragma unroll
        for (int j4 = 0; j4 < 4; j4++) {
            float4 v;
            v.x = vacc[tt][j4 * 4 + 0]; v.y = vacc[tt][j4 * 4 + 1];
            v.z = vacc[tt][j4 * 4 + 2]; v.w = vacc[tt][j4 * 4 + 3];
            *(float4*)&vs[w][tt][lane * 16 + j4 * 4] = v;
        }
    __syncthreads();
    int d0 = tid * 4;
    #pragma unroll
    for (int tt = 0; tt < 4; tt++) {
        float4 a = *(const float4*)&vs[0][tt][d0];
        float4 b = *(const float4*)&vs[1][tt][d0];
        float4 cc = *(const float4*)&vs[2][tt][d0];
        float4 e = *(const float4*)&vs[3][tt][d0];
        float sv[4];
        sv[0] = a.x + b.x + cc.x + e.x;
        sv[1] = a.y + b.y + cc.y + e.y;
        sv[2] = a.z + b.z + cc.z + e.z;
        sv[3] = a.w + b.w + cc.w + e.w;
        short4v b1, b2;
        #pragma unroll
        for (int e2 = 0; e2 < 4; e2++) {
            short q = f2bf(sv[e2]);
            b1[e2] = q;
            b2[e2] = f2bf(sv[e2] - bf2f(q));
        }
        size_t row = ((size_t)(tg * 4 + tt) * 64 + n) * 1024 + d0;
        *(short4v*)(Vhi + row) = b1;
        *(short4v*)(Vlo + row) = b2;
    }
}

// ---------------- host launch ----------------
extern "C" void kernel_launch(void* const* d_in, const int* in_sizes, int n_in,
                              void* d_out, int out_size, void* d_ws, size_t ws_size,
                              hipStream_t stream) {
    const int*   tokens = (const int*)d_in[0];
    const float* imgf   = (const float*)d_in[1];
    const float* emb    = (const float*)d_in[2];
    const float* w_ih1  = (const float*)d_in[3];
    const float* w_hh1  = (const float*)d_in[4];
    const float* b_ih1  = (const float*)d_in[5];
    const float* b_hh1  = (const float*)d_in[6];
    const float* w_ih2  = (const float*)d_in[7];
    const float* w_hh2  = (const float*)d_in[8];
    const float* b_ih2  = (const float*)d_in[9];
    const float* b_hh2  = (const float*)d_in[10];
    float* out = (float*)d_out;
    char* ws = (char*)d_ws;

    unsigned* arrive1 = (unsigned*)(ws + OFF_C1);            // 256 dwords packed
    unsigned* arrive2 = (unsigned*)(ws + OFF_C1 + 4096u);    // 256 dwords packed
    short* H1hi   = (short*)(ws + OFF_H1HI);
    short* H1lo   = (short*)(ws + OFF_H1LO);
    float* H1f    = (float*)(ws + OFF_H1F);
    short* H2     = (short*)(ws + OFF_H1F);    // time-indexed h2 slots (after attn)
    short* X0hi   = (short*)(ws + OFF_X0HI);
    short* X0lo   = (short*)(ws + OFF_X0LO);
    short* Vhi    = (short*)(ws + OFF_X0HI);   // alias (X0 dead after X1 GEMM)
    short* Vlo    = (short*)(ws + OFF_X0LO);
    float* bias1p = (float*)(ws + OFF_B1);
    float* bias2p = (float*)(ws + OFF_B2);
    short* whh1hi = (short*)(ws + OFF_WHH1HI);
    short* whh1lo = (short*)(ws + OFF_WHH1LO);
    short* wih1hi = (short*)(ws + OFF_WIH1HI);
    short* wih1lo = (short*)(ws + OFF_WIH1LO);
    short* whh2hi = (short*)(ws + OFF_WHH2HI);
    short* wvhi   = (short*)(ws + OFF_WVHI);
    short* wvlo   = (short*)(ws + OFF_WVLO);
    short* wh2hi  = (short*)(ws + OFF_WH2HI);
    float* X12    = (float*)(ws + OFF_X12);
    short* dump   = (short*)(ws + OFF_X12);    // prep-time scratch, overwritten later

    // prep (cell state register-resident; t=0 skips h@W -> no h-slot zeroing;
    // barrier region zeroed with SYSTEM-scope stores so polls observe it)
    zero_slots<<<8, 256, 0, stream>>>((unsigned*)(ws + OFF_C1));   // 8KB
    perm_w_split<<<4096, 256, 0, stream>>>(w_hh1, whh1hi, whh1lo, 1024, 0);
    perm_w_split<<<4096, 256, 0, stream>>>(w_ih1, wih1hi, wih1lo, 1024, 0);
    perm_w_split<<<4096, 256, 0, stream>>>(w_hh2, whh2hi, dump, 1024, 0);
    perm_w_split<<<4096, 256, 0, stream>>>(w_ih2, wvhi, wvlo, 2048, 0);
    perm_w_split<<<4096, 256, 0, stream>>>(w_ih2, wh2hi, dump, 2048, 1024);
    bias_prep<<<16, 256, 0, stream>>>(b_ih1, b_hh1, b_ih2, b_hh2, bias1p, bias2p);
    gather_x0_split<<<2048, 256, 0, stream>>>(tokens, emb, X0hi, X0lo);

    // X1 = (X0hi+X0lo) @ (wih1hi+wih1lo)^T + bias1, triple-split, K=3072
    big_gemm<<<dim3(32, 16), 256, 0, stream>>>(
        X0hi, X0lo, X0hi, X0hi,
        wih1hi, wih1hi, wih1lo, wih1hi,
        bias1p, X12, 3072);

    // fused layer-1 recurrence (one normal launch, 32 steps inside)
    lstm1_fused<<<256, 256, 0, stream>>>(
        whh1hi, whh1lo, X12, H1hi, H1lo, H1f, arrive1);

    // batched attention (fp32 in, compensated double-bf16 out)
    attn_batch<<<dim3(64, 8), 256, 0, stream>>>(H1f, imgf, Vhi, Vlo);

    // X2 = v@wv (triple-split) + h1@wh + bias2, K=4096
    big_gemm<<<dim3(32, 16), 256, 0, stream>>>(
        Vhi, Vlo, Vhi, H1hi + 65536,
        wvhi, wvhi, wvlo, wh2hi,
        bias2p, X12, 4096);

    // fused layer-2 recurrence (one normal launch, 32 steps inside)
    lstm2_fused<<<256, 256, 0, stream>>>(
        whh2hi, X12, H2, out, arrive2);
}

// Round 8
// 1052.489 us; speedup vs baseline: 1.0859x; 1.0859x over previous
//
#include <hip/hip_runtime.h>
#include <math.h>

// ---------------- types ----------------
typedef __attribute__((ext_vector_type(8))) short bf16x8;
typedef __attribute__((ext_vector_type(4))) short short4v;
typedef __attribute__((ext_vector_type(4))) float f32x4;

__device__ __forceinline__ float sigm(float x) { return 1.f / (1.f + expf(-x)); }

__device__ __forceinline__ float bf2f(short x) {
    unsigned u = ((unsigned)(unsigned short)x) << 16;
    float f; __builtin_memcpy(&f, &u, 4); return f;
}
__device__ __forceinline__ short f2bf(float f) {
    unsigned u; __builtin_memcpy(&u, &f, 4);
    unsigned r = (u + 0x7fffu + ((u >> 16) & 1u)) >> 16;
    return (short)r;
}

// ---------------- barrier v7: tree + private release lines ----------------
// Lesson r6/r7: uncached system-scope polls contend per LINE. v6 tree: 255
// blocks polled ONE release word (~0.57 reads/ns on one IF line -> queueing).
// v7 flat: 16K pollers on 16 lines -> worse. Fix: every polled line has
// EXACTLY ONE reader. Arrive = per-block 128B slot (aggregator thread tid
// reads slot tid). Release = 256 PRIVATE lines; block 0's 256 threads fan the
// release value out (parallel uncached stores), waiter g's thread 0 polls only
// line g. Values monotonic (t+1); region zeroed via system-scope stores.
__device__ __forceinline__ unsigned sys_ld(const unsigned* p) {
    return __hip_atomic_load(p, __ATOMIC_RELAXED, __HIP_MEMORY_SCOPE_SYSTEM);
}
__device__ __forceinline__ void sys_st(unsigned* p, unsigned v) {
    __hip_atomic_store(p, v, __ATOMIC_RELAXED, __HIP_MEMORY_SCOPE_SYSTEM);
}

// ---------------- workspace layout (byte offsets) ----------------
#define OFF_C1      0u           // barrier region 128KB (zeroed in-graph):
                                 // arrive1@0 (32KB), release1@32768 (32KB),
                                 // arrive2@65536 (32KB), release2@98304 (32KB)
#define OFF_H1HI    786432u      // 33 x 64x1024 bf16  4325376 (slot0 never read)
#define OFF_H1LO    5111808u     // 33 x 64x1024 bf16  4325376
#define OFF_H1F     9437184u     // 32 x 64x1024 f32 (lstm1 out) -> reused as
                                 // time-indexed H2 slots by lstm2
#define OFF_X0HI    17825792u    // 2048x1024 bf16 4194304  (aliased by VHI later)
#define OFF_X0LO    22020096u    // 2048x1024 bf16 4194304  (aliased by VLO later)
#define OFF_B1      26214400u    // 4096 f32 16384
#define OFF_B2      26230784u    // 4096 f32 16384
#define OFF_WHH1HI  26247168u    // 4096x1024 bf16 8388608
#define OFF_WHH1LO  34635776u
#define OFF_WIH1HI  43024384u
#define OFF_WIH1LO  51412992u
#define OFF_WHH2HI  59801600u
#define OFF_WVHI    68190208u
#define OFF_WVLO    76578816u
#define OFF_WH2HI   84967424u
#define OFF_X12     93356032u    // 2048x4096 f32 33554432 (also lo-dump during prep)

// ---------------- prep kernels ----------------
__global__ __launch_bounds__(256) void zero_ws(float4* __restrict__ p) {
    int i = blockIdx.x * 256 + threadIdx.x;
    p[i] = make_float4(0.f, 0.f, 0.f, 0.f);
}

// slot region zeroed with SYSTEM-scope (cache-bypass) stores so system polls
// observe the zeros.
__global__ __launch_bounds__(256) void zero_slots(unsigned* __restrict__ p) {
    int i = blockIdx.x * 256 + threadIdx.x;   // 128 blocks -> 32768 u32 = 128KB
    __hip_atomic_store(p + i, 0u, __ATOMIC_RELAXED, __HIP_MEMORY_SCOPE_SYSTEM);
}

__global__ __launch_bounds__(256) void perm_w_split(const float* __restrict__ src,
                                                    short* __restrict__ hi,
                                                    short* __restrict__ lo,
                                                    int rs, int co) {
    int idx = blockIdx.x * 256 + threadIdx.x;   // 4096 blocks
    int jp = idx >> 8;
    int kq = idx & 255;
    int jsrc = (jp & 3) * 1024 + (jp >> 2);
    float4 v = *(const float4*)(src + (size_t)jsrc * rs + co + kq * 4);
    float a[4] = {v.x, v.y, v.z, v.w};
    short4v h, l;
    #pragma unroll
    for (int e = 0; e < 4; e++) {
        short q = f2bf(a[e]);
        h[e] = q;
        l[e] = f2bf(a[e] - bf2f(q));
    }
    *(short4v*)(hi + (size_t)jp * 1024 + kq * 4) = h;
    *(short4v*)(lo + (size_t)jp * 1024 + kq * 4) = l;
}

__global__ __launch_bounds__(256) void bias_prep(
    const float* __restrict__ bi1, const float* __restrict__ bh1,
    const float* __restrict__ bi2, const float* __restrict__ bh2,
    float* __restrict__ b1p, float* __restrict__ b2p) {
    int jp = blockIdx.x * 256 + threadIdx.x;     // 16 blocks
    int j = (jp & 3) * 1024 + (jp >> 2);
    b1p[jp] = bi1[j] + bh1[j];
    b2p[jp] = bi2[j] + bh2[j];
}

__global__ __launch_bounds__(256) void gather_x0_split(
    const int* __restrict__ tokens, const float* __restrict__ emb,
    short* __restrict__ hi, short* __restrict__ lo) {
    int idx = blockIdx.x * 256 + threadIdx.x;    // 2048 blocks
    int p = idx >> 8;
    int k0 = (idx & 255) * 4;
    int tok = tokens[p];
    float4 v = *(const float4*)(emb + (size_t)tok * 1024 + k0);
    float a[4] = {v.x, v.y, v.z, v.w};
    short4v h, l;
    #pragma unroll
    for (int e = 0; e < 4; e++) {
        short q = f2bf(a[e]);
        h[e] = q;
        l[e] = f2bf(a[e] - bf2f(q));
    }
    *(short4v*)(hi + (size_t)p * 1024 + k0) = h;
    *(short4v*)(lo + (size_t)p * 1024 + k0) = l;
}

// ---------------- big GEMM (unchanged) ----------------
__global__ __launch_bounds__(256) void big_gemm(
    const short* __restrict__ A0, const short* __restrict__ A1s,
    const short* __restrict__ A2s, const short* __restrict__ A3s,
    const short* __restrict__ B0, const short* __restrict__ B1s,
    const short* __restrict__ B2s, const short* __restrict__ B3s,
    const float* __restrict__ bias, float* __restrict__ C, int K) {
    __shared__ short As[128 * 40];
    __shared__ short Bs[128 * 40];
    int tid = threadIdx.x;
    int n0 = blockIdx.x * 128;
    int m0 = blockIdx.y * 128;
    int lane = tid & 63, w = tid >> 6;
    int wm = (w >> 1) * 64, wn = (w & 1) * 64;
    int quad = lane >> 4, l16 = lane & 15;
    int srow = tid >> 2;
    int skc = (tid & 3) * 8;

    f32x4 acc[4][4];
    f32x4 z4 = {0.f, 0.f, 0.f, 0.f};
    #pragma unroll
    for (int i = 0; i < 4; i++)
        #pragma unroll
        for (int j = 0; j < 4; j++) acc[i][j] = z4;

    for (int k0 = 0; k0 < K; k0 += 32) {
        int seg = k0 >> 10;
        const short* Ab = (seg == 0) ? A0 : (seg == 1) ? A1s : (seg == 2) ? A2s : A3s;
        const short* Bb = (seg == 0) ? B0 : (seg == 1) ? B1s : (seg == 2) ? B2s : B3s;
        int kk = (k0 & 1023) + skc;
        const short* ga = Ab + (size_t)(m0 + srow) * 1024 + kk;
        const short* gb = Bb + (size_t)(n0 + srow) * 1024 + kk;
        bf16x8 av0 = *(const bf16x8*)ga;
        bf16x8 av1 = *(const bf16x8*)(ga + 64 * 1024);
        bf16x8 bv0 = *(const bf16x8*)gb;
        bf16x8 bv1 = *(const bf16x8*)(gb + 64 * 1024);
        __syncthreads();
        *(bf16x8*)&As[srow * 40 + skc] = av0;
        *(bf16x8*)&As[(srow + 64) * 40 + skc] = av1;
        *(bf16x8*)&Bs[srow * 40 + skc] = bv0;
        *(bf16x8*)&Bs[(srow + 64) * 40 + skc] = bv1;
        __syncthreads();
        bf16x8 af[4], bfr[4];
        #pragma unroll
        for (int im = 0; im < 4; im++)
            af[im] = *(const bf16x8*)&As[(wm + im * 16 + l16) * 40 + quad * 8];
        #pragma unroll
        for (int in = 0; in < 4; in++)
            bfr[in] = *(const bf16x8*)&Bs[(wn + in * 16 + l16) * 40 + quad * 8];
        #pragma unroll
        for (int im = 0; im < 4; im++)
            #pragma unroll
            for (int in = 0; in < 4; in++)
                acc[im][in] = __builtin_amdgcn_mfma_f32_16x16x32_bf16(
                    af[im], bfr[in], acc[im][in], 0, 0, 0);
    }
    #pragma unroll
    for (int in = 0; in < 4; in++) {
        int j = n0 + wn + in * 16 + l16;
        float bsv = bias[j];
        #pragma unroll
        for (int im = 0; im < 4; im++) {
            #pragma unroll
            for (int r = 0; r < 4; r++) {
                int p = m0 + wm + im * 16 + quad * 4 + r;
                C[(size_t)p * 4096 + j] = acc[im][in][r] + bsv;
            }
        }
    }
}

// ---------------- fused layer-1 recurrence (persistent, tree barrier) --------
// 256 blocks x 256 thr. Block g owns gate-rows [g*16,g*16+16) of whh1.
// W-hi in LDS; W-lo from global (L2-resident). Cell state register-resident.
// h written via shfl-gathered 8B sc1 stores into TIME-INDEXED slots; t=0
// skips h@W MFMA. Tail: gather-stores -> syncthreads (drain) -> arrive slot ->
// H1f store + X12[t+1] prefetch (in flight) -> tree wait (private lines).
__global__ __launch_bounds__(256, 1) void lstm1_fused(
    const short* __restrict__ Whi, const short* __restrict__ Wlo,
    const float* __restrict__ X12,
    short* __restrict__ H1hi, short* __restrict__ H1lo,
    float* __restrict__ H1f,
    unsigned* __restrict__ arrive, unsigned* __restrict__ release) {
    __shared__ short wsh[16 * 1032];
    __shared__ float red[4 * 64 * 16];

    int tid = threadIdx.x;
    int lane = tid & 63, w = tid >> 6;
    int quad = lane >> 4, l16 = lane & 15;
    int g = blockIdx.x;
    int kbase = w * 256;

    // stage hi-weight slice into LDS once
    for (int i = tid; i < 2048; i += 256) {
        int r = i >> 7;
        int k = (i & 127) * 8;
        *(bf16x8*)&wsh[r * 1032 + k] =
            *(const bf16x8*)(Whi + (size_t)(g * 16 + r) * 1024 + k);
    }

    int s = tid >> 2, dl = tid & 3;
    int d = g * 4 + dl;
    float creg = 0.f;           // register-resident cell state

    __syncthreads();

    const short* bhp = &wsh[l16 * 1032 + kbase + quad * 8];
    const short* blp = Wlo + (size_t)(g * 16 + l16) * 1024 + kbase + quad * 8;
    const float* xgp = X12 + (size_t)s * 4096 + g * 16 + dl * 4;

    float4 xg = *(const float4*)xgp;   // step-0 gate-bias slice

    for (int t = 0; t < 32; t++) {
        f32x4 acc[4];
        f32x4 z4 = {0.f, 0.f, 0.f, 0.f};
        acc[0] = z4; acc[1] = z4; acc[2] = z4; acc[3] = z4;

        if (t > 0) {   // h1[0] == 0 -> skip MFMA at t=0
            const short* ah = H1hi + (size_t)t * 65536 + (size_t)l16 * 1024 + kbase + quad * 8;
            const short* al = H1lo + (size_t)t * 65536 + (size_t)l16 * 1024 + kbase + quad * 8;
            #pragma unroll
            for (int i = 0; i < 8; i++) {
                int k = i * 32;
                bf16x8 Bh = *(const bf16x8*)(bhp + k);
                bf16x8 Bl = *(const bf16x8*)(blp + k);
                #pragma unroll
                for (int mt = 0; mt < 4; mt++) {
                    bf16x8 Ah = *(const bf16x8*)(ah + mt * 16 * 1024 + k);
                    bf16x8 Al = *(const bf16x8*)(al + mt * 16 * 1024 + k);
                    acc[mt] = __builtin_amdgcn_mfma_f32_16x16x32_bf16(Ah, Bh, acc[mt], 0, 0, 0);
                    acc[mt] = __builtin_amdgcn_mfma_f32_16x16x32_bf16(Al, Bh, acc[mt], 0, 0, 0);
                    acc[mt] = __builtin_amdgcn_mfma_f32_16x16x32_bf16(Ah, Bl, acc[mt], 0, 0, 0);
                }
            }
        }
        #pragma unroll
        for (int mt = 0; mt < 4; mt++)
            #pragma unroll
            for (int r = 0; r < 4; r++) {
                int sr = mt * 16 + quad * 4 + r;
                red[(w * 64 + sr) * 16 + l16] = acc[mt][r];
            }
        __syncthreads();

        float gi = 0.f, gf = 0.f, gg = 0.f, go = 0.f;
        #pragma unroll
        for (int w2 = 0; w2 < 4; w2++) {
            const float* rp = &red[(w2 * 64 + s) * 16 + dl * 4];
            gi += rp[0]; gf += rp[1]; gg += rp[2]; go += rp[3];
        }
        gi += xg.x; gf += xg.y; gg += xg.z; go += xg.w;
        float cn = sigm(gf) * creg + sigm(gi) * tanhf(gg);
        creg = cn;
        float hn = sigm(go) * tanhf(cn);
        short q = f2bf(hn);
        short ql = f2bf(hn - bf2f(q));

        // shfl-gather 4 lanes' (q,ql) -> lane dl==0 stores 8B per buffer (sc1)
        unsigned pr = ((unsigned)(unsigned short)q) |
                      (((unsigned)(unsigned short)ql) << 16);
        int lb = lane & ~3;
        unsigned p0 = __shfl(pr, lb + 0, 64);
        unsigned p1 = __shfl(pr, lb + 1, 64);
        unsigned p2 = __shfl(pr, lb + 2, 64);
        unsigned p3 = __shfl(pr, lb + 3, 64);
        if (dl == 0) {
            unsigned long long hi4 =
                (unsigned long long)(p0 & 0xffffu) |
                ((unsigned long long)(p1 & 0xffffu) << 16) |
                ((unsigned long long)(p2 & 0xffffu) << 32) |
                ((unsigned long long)(p3 & 0xffffu) << 48);
            unsigned long long lo4 =
                (unsigned long long)(p0 >> 16) |
                ((unsigned long long)(p1 >> 16) << 16) |
                ((unsigned long long)(p2 >> 16) << 32) |
                ((unsigned long long)(p3 >> 16) << 48);
            __hip_atomic_store(
                (unsigned long long*)&H1hi[(size_t)(t + 1) * 65536 + s * 1024 + g * 4],
                hi4, __ATOMIC_RELAXED, __HIP_MEMORY_SCOPE_AGENT);
            __hip_atomic_store(
                (unsigned long long*)&H1lo[(size_t)(t + 1) * 65536 + s * 1024 + g * 4],
                lo4, __ATOMIC_RELAXED, __HIP_MEMORY_SCOPE_AGENT);
        }
        __syncthreads();                       // drain: gathered stores acked
        if (t != 31) {
            unsigned tgt = (unsigned)(t + 1);
            if (tid == 0) sys_st(arrive + (size_t)g * 32, tgt);
            // off-chain work, in flight during the wait window:
            H1f[(size_t)t * 65536 + s * 1024 + d] = hn;   // consumed by attn later
            xg = *(const float4*)(xgp + (size_t)(t + 1) * 262144);
            if (g == 0) {
                // aggregator: thread tid polls arrival slot tid (1 reader/line)
                const unsigned* my = arrive + (size_t)tid * 32;
                while (sys_ld(my) < tgt) __builtin_amdgcn_s_sleep(2);
                __syncthreads();
                // fan-out: 256 private release lines, one per waiter block
                sys_st(release + (size_t)tid * 32, tgt);
            } else {
                // waiter: thread 0 polls its OWN private release line
                if (tid == 0)
                    while (sys_ld(release + (size_t)g * 32) < tgt)
                        __builtin_amdgcn_s_sleep(2);
                __syncthreads();
            }
            asm volatile("" ::: "memory");
        } else {
            H1f[(size_t)t * 65536 + s * 1024 + d] = hn;
        }
    }
}

// ---------------- fused layer-2 recurrence (persistent, tree barrier) --------
// H2 is TIME-INDEXED (33 slots, lives in the dead H1F region); t=0 skips MFMA.
__global__ __launch_bounds__(256, 1) void lstm2_fused(
    const short* __restrict__ W, const float* __restrict__ X12,
    short* __restrict__ H2,
    float* __restrict__ out,
    unsigned* __restrict__ arrive, unsigned* __restrict__ release) {
    __shared__ short wsh[16 * 1032];
    __shared__ float red[4 * 64 * 16];

    int tid = threadIdx.x;
    int lane = tid & 63, w = tid >> 6;
    int quad = lane >> 4, l16 = lane & 15;
    int g = blockIdx.x;
    int kbase = w * 256;

    for (int i = tid; i < 2048; i += 256) {
        int r = i >> 7;
        int k = (i & 127) * 8;
        *(bf16x8*)&wsh[r * 1032 + k] =
            *(const bf16x8*)(W + (size_t)(g * 16 + r) * 1024 + k);
    }

    int s = tid >> 2, dl = tid & 3;
    int d = g * 4 + dl;
    float creg = 0.f;

    __syncthreads();

    const short* bp = &wsh[l16 * 1032 + kbase + quad * 8];
    const float* xgp = X12 + (size_t)s * 4096 + g * 16 + dl * 4;

    float4 xg = *(const float4*)xgp;

    for (int t = 0; t < 32; t++) {
        f32x4 acc[4];
        f32x4 z4 = {0.f, 0.f, 0.f, 0.f};
        acc[0] = z4; acc[1] = z4; acc[2] = z4; acc[3] = z4;

        if (t > 0) {   // h2[0] == 0 -> skip MFMA at t=0
            const short* ar = H2 + (size_t)t * 65536 + (size_t)l16 * 1024 + kbase + quad * 8;
            #pragma unroll
            for (int i = 0; i < 8; i++) {
                int k = i * 32;
                bf16x8 b = *(const bf16x8*)(bp + k);
                #pragma unroll
                for (int mt = 0; mt < 4; mt++) {
                    bf16x8 a = *(const bf16x8*)(ar + mt * 16 * 1024 + k);
                    acc[mt] = __builtin_amdgcn_mfma_f32_16x16x32_bf16(a, b, acc[mt], 0, 0, 0);
                }
            }
        }
        #pragma unroll
        for (int mt = 0; mt < 4; mt++)
            #pragma unroll
            for (int r = 0; r < 4; r++) {
                int sr = mt * 16 + quad * 4 + r;
                red[(w * 64 + sr) * 16 + l16] = acc[mt][r];
            }
        __syncthreads();

        float gi = 0.f, gf = 0.f, gg = 0.f, go = 0.f;
        #pragma unroll
        for (int w2 = 0; w2 < 4; w2++) {
            const float* rp = &red[(w2 * 64 + s) * 16 + dl * 4];
            gi += rp[0]; gf += rp[1]; gg += rp[2]; go += rp[3];
        }
        gi += xg.x; gf += xg.y; gg += xg.z; go += xg.w;
        float cn = sigm(gf) * creg + sigm(gi) * tanhf(gg);
        creg = cn;
        float hn = sigm(go) * tanhf(cn);

        // shfl-gather 4 lanes' bf16 h -> lane dl==0 stores one 8B sc1 store
        unsigned pr = (unsigned)(unsigned short)f2bf(hn);
        int lb = lane & ~3;
        unsigned p0 = __shfl(pr, lb + 0, 64);
        unsigned p1 = __shfl(pr, lb + 1, 64);
        unsigned p2 = __shfl(pr, lb + 2, 64);
        unsigned p3 = __shfl(pr, lb + 3, 64);
        if (dl == 0) {
            unsigned long long h4 =
                (unsigned long long)(p0 & 0xffffu) |
                ((unsigned long long)(p1 & 0xffffu) << 16) |
                ((unsigned long long)(p2 & 0xffffu) << 32) |
                ((unsigned long long)(p3 & 0xffffu) << 48);
            __hip_atomic_store(
                (unsigned long long*)&H2[(size_t)(t + 1) * 65536 + s * 1024 + g * 4],
                h4, __ATOMIC_RELAXED, __HIP_MEMORY_SCOPE_AGENT);
        }
        __syncthreads();                       // drain
        if (t != 31) {
            unsigned tgt = (unsigned)(t + 1);
            if (tid == 0) sys_st(arrive + (size_t)g * 32, tgt);
            out[(size_t)t * 65536 + s * 1024 + d] = hn;   // host-visible later
            xg = *(const float4*)(xgp + (size_t)(t + 1) * 262144);
            if (g == 0) {
                const unsigned* my = arrive + (size_t)tid * 32;
                while (sys_ld(my) < tgt) __builtin_amdgcn_s_sleep(2);
                __syncthreads();
                sys_st(release + (size_t)tid * 32, tgt);
            } else {
                if (tid == 0)
                    while (sys_ld(release + (size_t)g * 32) < tgt)
                        __builtin_amdgcn_s_sleep(2);
                __syncthreads();
            }
            asm volatile("" ::: "memory");
        } else {
            out[(size_t)t * 65536 + s * 1024 + d] = hn;
        }
    }
}

// ---------------- batched attention (fp32, unchanged) ----------------
__global__ __launch_bounds__(256) void attn_batch(
    const float* __restrict__ H1f, const float* __restrict__ F,
    short* __restrict__ Vhi, short* __restrict__ Vlo) {
    __shared__ float vs[4][4][1024];
    int n = blockIdx.x, tg = blockIdx.y;
    int tid = threadIdx.x, lane = tid & 63, w = tid >> 6;

    float h[4][16];
    #pragma unroll
    for (int tt = 0; tt < 4; tt++) {
        const float* hp = H1f + ((size_t)((tg * 4 + tt) * 64 + n)) * 1024 + lane * 16;
        #pragma unroll
        for (int j = 0; j < 4; j++) {
            float4 v = *(const float4*)(hp + j * 4);
            h[tt][j * 4 + 0] = v.x; h[tt][j * 4 + 1] = v.y;
            h[tt][j * 4 + 2] = v.z; h[tt][j * 4 + 3] = v.w;
        }
    }
    float vacc[4][16];
    #pragma unroll
    for (int tt = 0; tt < 4; tt++)
        #pragma unroll
        for (int j = 0; j < 16; j++) vacc[tt][j] = 0.f;

    const float* Fn = F + ((size_t)n * 196) * 1024 + lane * 16;
    for (int l = w; l < 196; l += 4) {
        const float* fr = Fn + (size_t)l * 1024;
        float f[16];
        #pragma unroll
        for (int j = 0; j < 4; j++) {
            float4 v = *(const float4*)(fr + j * 4);
            f[j * 4 + 0] = v.x; f[j * 4 + 1] = v.y;
            f[j * 4 + 2] = v.z; f[j * 4 + 3] = v.w;
        }
        float p[4] = {0.f, 0.f, 0.f, 0.f};
        #pragma unroll
        for (int tt = 0; tt < 4; tt++)
            #pragma unroll
            for (int j = 0; j < 16; j++) p[tt] += f[j] * h[tt][j];
        #pragma unroll
        for (int off = 32; off > 0; off >>= 1) {
            #pragma unroll
            for (int tt = 0; tt < 4; tt++) p[tt] += __shfl_xor(p[tt], off, 64);
        }
        #pragma unroll
        for (int tt = 0; tt < 4; tt++)
            #pragma unroll
            for (int j = 0; j < 16; j++) vacc[tt][j] += p[tt] * f[j];
    }
    #pragma unroll
    for (int tt = 0; tt < 4; tt++)
        #pragma unroll
        for (int j4 = 0; j4 < 4; j4++) {
            float4 v;
            v.x = vacc[tt][j4 * 4 + 0]; v.y = vacc[tt][j4 * 4 + 1];
            v.z = vacc[tt][j4 * 4 + 2]; v.w = vacc[tt][j4 * 4 + 3];
            *(float4*)&vs[w][tt][lane * 16 + j4 * 4] = v;
        }
    __syncthreads();
    int d0 = tid * 4;
    #pragma unroll
    for (int tt = 0; tt < 4; tt++) {
        float4 a = *(const float4*)&vs[0][tt][d0];
        float4 b = *(const float4*)&vs[1][tt][d0];
        float4 cc = *(const float4*)&vs[2][tt][d0];
        float4 e = *(const float4*)&vs[3][tt][d0];
        float sv[4];
        sv[0] = a.x + b.x + cc.x + e.x;
        sv[1] = a.y + b.y + cc.y + e.y;
        sv[2] = a.z + b.z + cc.z + e.z;
        sv[3] = a.w + b.w + cc.w + e.w;
        short4v b1, b2;
        #pragma unroll
        for (int e2 = 0; e2 < 4; e2++) {
            short q = f2bf(sv[e2]);
            b1[e2] = q;
            b2[e2] = f2bf(sv[e2] - bf2f(q));
        }
        size_t row = ((size_t)(tg * 4 + tt) * 64 + n) * 1024 + d0;
        *(short4v*)(Vhi + row) = b1;
        *(short4v*)(Vlo + row) = b2;
    }
}

// ---------------- host launch ----------------
extern "C" void kernel_launch(void* const* d_in, const int* in_sizes, int n_in,
                              void* d_out, int out_size, void* d_ws, size_t ws_size,
                              hipStream_t stream) {
    const int*   tokens = (const int*)d_in[0];
    const float* imgf   = (const float*)d_in[1];
    const float* emb    = (const float*)d_in[2];
    const float* w_ih1  = (const float*)d_in[3];
    const float* w_hh1  = (const float*)d_in[4];
    const float* b_ih1  = (const float*)d_in[5];
    const float* b_hh1  = (const float*)d_in[6];
    const float* w_ih2  = (const float*)d_in[7];
    const float* w_hh2  = (const float*)d_in[8];
    const float* b_ih2  = (const float*)d_in[9];
    const float* b_hh2  = (const float*)d_in[10];
    float* out = (float*)d_out;
    char* ws = (char*)d_ws;

    unsigned* arrive1  = (unsigned*)(ws + OFF_C1);            // 256 x 128B
    unsigned* release1 = (unsigned*)(ws + OFF_C1 + 32768u);   // 256 x 128B
    unsigned* arrive2  = (unsigned*)(ws + OFF_C1 + 65536u);   // 256 x 128B
    unsigned* release2 = (unsigned*)(ws + OFF_C1 + 98304u);   // 256 x 128B
    short* H1hi   = (short*)(ws + OFF_H1HI);
    short* H1lo   = (short*)(ws + OFF_H1LO);
    float* H1f    = (float*)(ws + OFF_H1F);
    short* H2     = (short*)(ws + OFF_H1F);    // time-indexed h2 slots (after attn)
    short* X0hi   = (short*)(ws + OFF_X0HI);
    short* X0lo   = (short*)(ws + OFF_X0LO);
    short* Vhi    = (short*)(ws + OFF_X0HI);   // alias (X0 dead after X1 GEMM)
    short* Vlo    = (short*)(ws + OFF_X0LO);
    float* bias1p = (float*)(ws + OFF_B1);
    float* bias2p = (float*)(ws + OFF_B2);
    short* whh1hi = (short*)(ws + OFF_WHH1HI);
    short* whh1lo = (short*)(ws + OFF_WHH1LO);
    short* wih1hi = (short*)(ws + OFF_WIH1HI);
    short* wih1lo = (short*)(ws + OFF_WIH1LO);
    short* whh2hi = (short*)(ws + OFF_WHH2HI);
    short* wvhi   = (short*)(ws + OFF_WVHI);
    short* wvlo   = (short*)(ws + OFF_WVLO);
    short* wh2hi  = (short*)(ws + OFF_WH2HI);
    float* X12    = (float*)(ws + OFF_X12);
    short* dump   = (short*)(ws + OFF_X12);    // prep-time scratch, overwritten later

    // prep (cell state register-resident; t=0 skips h@W -> no h-slot zeroing;
    // barrier region zeroed with SYSTEM-scope stores so polls observe it)
    zero_slots<<<128, 256, 0, stream>>>((unsigned*)(ws + OFF_C1));  // 128KB
    perm_w_split<<<4096, 256, 0, stream>>>(w_hh1, whh1hi, whh1lo, 1024, 0);
    perm_w_split<<<4096, 256, 0, stream>>>(w_ih1, wih1hi, wih1lo, 1024, 0);
    perm_w_split<<<4096, 256, 0, stream>>>(w_hh2, whh2hi, dump, 1024, 0);
    perm_w_split<<<4096, 256, 0, stream>>>(w_ih2, wvhi, wvlo, 2048, 0);
    perm_w_split<<<4096, 256, 0, stream>>>(w_ih2, wh2hi, dump, 2048, 1024);
    bias_prep<<<16, 256, 0, stream>>>(b_ih1, b_hh1, b_ih2, b_hh2, bias1p, bias2p);
    gather_x0_split<<<2048, 256, 0, stream>>>(tokens, emb, X0hi, X0lo);

    // X1 = (X0hi+X0lo) @ (wih1hi+wih1lo)^T + bias1, triple-split, K=3072
    big_gemm<<<dim3(32, 16), 256, 0, stream>>>(
        X0hi, X0lo, X0hi, X0hi,
        wih1hi, wih1hi, wih1lo, wih1hi,
        bias1p, X12, 3072);

    // fused layer-1 recurrence (one normal launch, 32 steps inside)
    lstm1_fused<<<256, 256, 0, stream>>>(
        whh1hi, whh1lo, X12, H1hi, H1lo, H1f, arrive1, release1);

    // batched attention (fp32 in, compensated double-bf16 out)
    attn_batch<<<dim3(64, 8), 256, 0, stream>>>(H1f, imgf, Vhi, Vlo);

    // X2 = v@wv (triple-split) + h1@wh + bias2, K=4096
    big_gemm<<<dim3(32, 16), 256, 0, stream>>>(
        Vhi, Vlo, Vhi, H1hi + 65536,
        wvhi, wvhi, wvlo, wh2hi,
        bias2p, X12, 4096);

    // fused layer-2 recurrence (one normal launch, 32 steps inside)
    lstm2_fused<<<256, 256, 0, stream>>>(
        whh2hi, X12, H2, out, arrive2, release2);
}